// Round 4
// baseline (1093.225 us; speedup 1.0000x reference)
//
#include <hip/hip_runtime.h>
#include <hip/hip_bf16.h>
#include <cstdint>
#include <cstddef>

#define NN 10000
#define NE 160000

typedef unsigned short u16;

__device__ __forceinline__ float b2f(u16 u){
    union { uint32_t i; float f; } v; v.i = ((uint32_t)u) << 16; return v.f;
}
__device__ __forceinline__ float silu_f(float x){ return x / (1.f + __expf(-x)); }

// ---------------- workspace layout (4-byte word offsets), total ~19.3 MB ----------------
constexpr size_t W_FLAG = 0;                       // 16
constexpr size_t W_CNT  = 16;                      // 10000
constexpr size_t W_OFFS = 10016;                   // 10001
constexpr size_t W_CUR  = 20032;                   // 10000
constexpr size_t W_ORD  = 30032;                   // 160000
constexpr size_t W_POS  = 190032;                  // 30000
constexpr size_t W_ATT  = 220032;                  // 100000
constexpr size_t W_SHF  = 320032;                  // 480000
constexpr size_t W_WGT  = 800032;                  // 166992
constexpr size_t OW_EMB = 0;
constexpr size_t OW_UP0 = OW_EMB + 640;
constexpr size_t OW_R10 = OW_UP0 + 4096;
constexpr size_t OW_R20 = OW_R10 + 512;
constexpr size_t OW_R30 = OW_R20 + 4096;
constexpr size_t OW_MIX0= OW_R30 + 16384;
constexpr size_t OW_SC0 = OW_MIX0 + 16384;
constexpr size_t OW_PR0 = OW_SC0 + 40960;
constexpr size_t OW_UP1 = OW_PR0 + 192;
constexpr size_t OW_R11 = OW_UP1 + 4096;
constexpr size_t OW_R21 = OW_R11 + 512;
constexpr size_t OW_R31 = OW_R21 + 4096;
constexpr size_t OW_MIX1= OW_R31 + 16384;
constexpr size_t OW_SC1 = OW_MIX1 + 16384;
constexpr size_t OW_PR1 = OW_SC1 + 40960;
constexpr size_t OW_RD0 = OW_PR1 + 192;
constexpr size_t OW_ML1 = OW_RD0 + 64;
constexpr size_t OW_ML2 = OW_ML1 + 1024;
constexpr size_t W_BES  = W_WGT + 166992;          // [E,8]  f32
constexpr size_t W_NF0  = W_BES + (size_t)NE*8;    // [N,64]
constexpr size_t W_H    = W_NF0 + (size_t)NN*64;   // [N,64]
constexpr size_t W_A    = W_H   + (size_t)NN*64;   // [N,64]
constexpr size_t W_NF1  = W_A   + (size_t)NN*64;   // [N,64]  (k=0 plane of nf1)

// ---------------- dtype detection via exact one-hot structure of attrs ----------------
__global__ void k_detect(const uint32_t* __restrict__ attrs, int* __restrict__ flag){
    __shared__ int cnt_s;
    if (threadIdx.x == 0) cnt_s = 0;
    __syncthreads();
    int c = 0;
    for (int i = threadIdx.x; i < 50000; i += 256){
        uint32_t v = attrs[i];
        if (v != 0u && v != 0x3F800000u) c++;
    }
    atomicAdd(&cnt_s, c);
    __syncthreads();
    if (threadIdx.x == 0) flag[0] = (cnt_s > 100) ? 1 : 0;   // 1 = inputs are bf16
}

// ---------------- convert all float inputs -> fp32 workspace ----------------
struct PrepArgs { const void* s[21]; float* d[21]; int n[21]; };
__global__ void k_prep(PrepArgs a, const int* __restrict__ flag){
    int bf = flag[0];
    int stride = gridDim.x * blockDim.x;
    int t0 = blockIdx.x * blockDim.x + threadIdx.x;
    for (int k = 0; k < 21; k++){
        float* d = a.d[k]; int n = a.n[k];
        if (bf){
            const u16* s = (const u16*)a.s[k];
            for (int i = t0; i < n; i += stride) d[i] = b2f(s[i]);
        } else {
            const float* s = (const float*)a.s[k];
            for (int i = t0; i < n; i += stride) d[i] = s[i];
        }
    }
}

// ---------------- edge bessel features (Y not needed: only l=0 path is live) ----------------
__global__ void k_geom(const float* __restrict__ pos, const float* __restrict__ shf,
                       const int* __restrict__ snd, const int* __restrict__ rcv,
                       float* __restrict__ bess){
    int e = blockIdx.x * 256 + threadIdx.x;
    if (e >= NE) return;
    int s = snd[e], r = rcv[e];
    float vx = pos[r*3+0] - pos[s*3+0] + shf[e*3+0];
    float vy = pos[r*3+1] - pos[s*3+1] + shf[e*3+1];
    float vz = pos[r*3+2] - pos[s*3+2] + shf[e*3+2];
    float rr = sqrtf(vx*vx + vy*vy + vz*vz);
    float xr = rr * 0.1f;
    float x2 = xr*xr; float x5 = x2*x2*xr;
    float env = 1.f - 21.f*x5 + 35.f*x5*xr - 15.f*x5*x2;
    if (xr >= 1.f) env = 0.f;
    float scl = 0.4472135954999579f * env / (rr + 1e-9f);  // sqrt(2/10)*env/(r+eps)
    float* be = bess + (size_t)e*8;
    #pragma unroll
    for (int n = 1; n <= 8; n++)
        be[n-1] = scl * sinf((float)n * 3.14159265358979323846f * rr * 0.1f);
}

// ---------------- CSR build ----------------
__global__ void k_hist(const int* __restrict__ rcv, int* __restrict__ cnt){
    int e = blockIdx.x * 256 + threadIdx.x;
    if (e < NE) atomicAdd(&cnt[rcv[e]], 1);
}
__global__ void k_scan(const int* __restrict__ cnt, int* __restrict__ offs, int* __restrict__ cur){
    __shared__ int part[1024];
    int t = threadIdx.x;
    int base = t * 10;
    int s = 0;
    for (int i = 0; i < 10; i++) if (base + i < NN) s += cnt[base + i];
    part[t] = s; __syncthreads();
    for (int d = 1; d < 1024; d <<= 1){
        int v = part[t];
        if (t >= d) v += part[t - d];
        __syncthreads();
        part[t] = v;
        __syncthreads();
    }
    int run = part[t] - s;
    for (int i = 0; i < 10; i++){
        int idx = base + i;
        if (idx < NN){ offs[idx] = run; cur[idx] = run; run += cnt[idx]; }
    }
    if (t == 1023) offs[NN] = part[1023];
}
__global__ void k_scatter(const int* __restrict__ rcv, int* __restrict__ cur, int* __restrict__ order){
    int e = blockIdx.x * 256 + threadIdx.x;
    if (e < NE){
        int p = atomicAdd(&cur[rcv[e]], 1);
        order[p] = e;
    }
}

// ---------------- nf0 = attrs @ w_embed ----------------
__global__ void k_embed(const float* __restrict__ attrs, const float* __restrict__ Wemb,
                        float* __restrict__ nf0){
    int t = blockIdx.x * 256 + threadIdx.x;
    int n = t >> 6;
    int l = t & 63;
    float acc = 0.f;
    #pragma unroll
    for (int s = 0; s < 10; s++) acc += attrs[n*10 + s] * Wemb[s*64 + l];
    nf0[n*64 + l] = acc;
}

// ---------------- h = nf(:,:,0) @ W_up ----------------
__global__ void k_h(const float* __restrict__ src, const float* __restrict__ W,
                    float* __restrict__ h){
    int t = blockIdx.x * 256 + threadIdx.x;
    int n = t >> 6;
    int l = t & 63;
    const float* row = src + (size_t)n*64;
    float acc = 0.f;
    #pragma unroll 8
    for (int g = 0; g < 64; g++) acc += row[g] * W[g*64 + l];
    h[n*64 + l] = acc;
}

// ---------------- fused radial-MLP (l=0 slot) + gather + segment-sum ----------------
// wave per node; lane = feature f.
__global__ __launch_bounds__(256) void k_msg(const int* __restrict__ offs, const int* __restrict__ order,
        const int* __restrict__ snd, const float* __restrict__ h, const float* __restrict__ bess,
        const float* __restrict__ W1, const float* __restrict__ W2, const float* __restrict__ W3,
        float* __restrict__ A){
    int wv = threadIdx.x >> 6;
    int n  = blockIdx.x * 4 + wv;          // 2500*4 == NN
    int l  = threadIdx.x & 63;
    float w1c[8];
    #pragma unroll
    for (int i = 0; i < 8; i++) w1c[i] = W1[i*64 + l];
    float w2c[64];
    #pragma unroll
    for (int j = 0; j < 64; j++) w2c[j] = W2[j*64 + l];
    float w3c[64];
    #pragma unroll
    for (int j = 0; j < 64; j++) w3c[j] = W3[j*256 + 4*l];   // l'=0 slot of feature l
    float acc = 0.f;
    int beg = __builtin_amdgcn_readfirstlane(offs[n]);
    int end = __builtin_amdgcn_readfirstlane(offs[n+1]);
    for (int p = beg; p < end; p++){
        int e = __builtin_amdgcn_readfirstlane(order[p]);
        int s = __builtin_amdgcn_readfirstlane(snd[e]);
        const float* be = bess + (size_t)e*8;
        float h1 = 0.f;
        #pragma unroll
        for (int i = 0; i < 8; i++) h1 += be[i] * w1c[i];
        h1 = silu_f(h1);
        float h2 = 0.f;
        #pragma unroll
        for (int j = 0; j < 64; j++) h2 += __shfl(h1, j) * w2c[j];
        h2 = silu_f(h2);
        float r = 0.f;
        #pragma unroll
        for (int j = 0; j < 64; j++) r += __shfl(h2, j) * w3c[j];
        acc += h[s*64 + l] * r;
    }
    A[n*64 + l] = acc * 0.0625f;
}

// ---------------- node update (mix k=0 + sc + poly) + readout ----------------
template<int LAST>
__global__ __launch_bounds__(256) void k_node(const float* __restrict__ A, const float* __restrict__ nf,
        const float* __restrict__ attrs, const float* __restrict__ Wmix0, const float* __restrict__ Wsc,
        const float* __restrict__ Wprod, const float* __restrict__ Wtail, const float* __restrict__ Wml2,
        float* __restrict__ nf1out, void* __restrict__ out, const int* __restrict__ flag){
    int wv = threadIdx.x >> 6;
    int n  = blockIdx.x * 4 + wv;
    int l  = threadIdx.x & 63;
    float Af  = A[n*64 + l];
    float nff = nf[n*64 + l];
    float am = 0.f;
    #pragma unroll 16
    for (int f = 0; f < 64; f++) am += __shfl(Af, f) * Wmix0[f*64 + l];
    float sc = 0.f;
    for (int s = 0; s < 10; s++){
        float av = attrs[n*10 + s];       // wave-uniform -> no divergence at the branch
        if (av != 0.f){
            const float* Ws = Wsc + s*4096;
            float t = 0.f;
            #pragma unroll 16
            for (int f = 0; f < 64; f++) t += __shfl(nff, f) * Ws[f*64 + l];
            sc += av * t;
        }
    }
    float poly = Wprod[l] + Wprod[64 + l]*am + Wprod[128 + l]*am*am;
    float val = am*poly + sc;
    float rv;
    if (LAST == 0){
        nf1out[n*64 + l] = val;
        rv = val * Wtail[l];                 // w_read0 [F,1]
    } else {
        // out1 MLP: ALL 64 lanes run the shfl loop (shfl from inactive lanes is
        // undefined on CDNA — this was the round-3 bug). Lanes >=16 compute a
        // duplicate column (l&15) and are masked to zero before the reduction.
        int lj = l & 15;
        float t = 0.f;
        #pragma unroll 16
        for (int g = 0; g < 64; g++){
            float vg = __shfl(val, g);
            t += vg * Wtail[g*16 + lj];
        }
        rv = (l < 16) ? (silu_f(t) * Wml2[lj]) : 0.f;
    }
    #pragma unroll
    for (int o2 = 32; o2; o2 >>= 1) rv += __shfl_down(rv, o2);
    if (l == 0){
        int idx = 2*n + LAST;
        if (flag[0]) ((__hip_bfloat16*)out)[idx] = __float2bfloat16(rv);
        else         ((float*)out)[idx] = rv;
    }
}

// ---------------- launch ----------------
extern "C" void kernel_launch(void* const* d_in, const int* in_sizes, int n_in,
                              void* d_out, int out_size, void* d_ws, size_t ws_size,
                              hipStream_t stream) {
    int*   iw = (int*)d_ws;
    float* fw = (float*)d_ws;
    const int* snd = (const int*)d_in[3];
    const int* rcv = (const int*)d_in[4];

    PrepArgs pa;
    const int    pidx[21] = {0,1,2, 5,6,7,8,9,10,11,12,13,14,15,16,17,18,19,20,21,22};
    const size_t pdst[21] = {W_POS, W_ATT, W_SHF,
        W_WGT+OW_EMB, W_WGT+OW_UP0, W_WGT+OW_R10, W_WGT+OW_R20, W_WGT+OW_R30,
        W_WGT+OW_MIX0, W_WGT+OW_SC0, W_WGT+OW_PR0,
        W_WGT+OW_UP1, W_WGT+OW_R11, W_WGT+OW_R21, W_WGT+OW_R31,
        W_WGT+OW_MIX1, W_WGT+OW_SC1, W_WGT+OW_PR1,
        W_WGT+OW_RD0, W_WGT+OW_ML1, W_WGT+OW_ML2};
    const int    pn[21]   = {30000, 100000, 480000,
        640, 4096, 512, 4096, 16384, 16384, 40960, 192,
        4096, 512, 4096, 16384, 16384, 40960, 192, 64, 1024, 16};
    for (int i = 0; i < 21; i++){
        pa.s[i] = d_in[pidx[i]];
        pa.d[i] = fw + pdst[i];
        pa.n[i] = pn[i];
    }

    hipMemsetAsync(iw + W_CNT, 0, NN * sizeof(int), stream);
    k_detect<<<1, 256, 0, stream>>>((const uint32_t*)d_in[1], iw + W_FLAG);
    k_prep<<<120, 256, 0, stream>>>(pa, iw + W_FLAG);
    k_geom<<<NE/256, 256, 0, stream>>>(fw + W_POS, fw + W_SHF, snd, rcv, fw + W_BES);
    k_hist<<<NE/256, 256, 0, stream>>>(rcv, iw + W_CNT);
    k_scan<<<1, 1024, 0, stream>>>(iw + W_CNT, iw + W_OFFS, iw + W_CUR);
    k_scatter<<<NE/256, 256, 0, stream>>>(rcv, iw + W_CUR, iw + W_ORD);
    k_embed<<<NN/4, 256, 0, stream>>>(fw + W_ATT, fw + W_WGT + OW_EMB, fw + W_NF0);
    // interaction 0 (k=0 plane only — k!=0 provably never reaches either output)
    k_h<<<NN/4, 256, 0, stream>>>(fw + W_NF0, fw + W_WGT + OW_UP0, fw + W_H);
    k_msg<<<NN/4, 256, 0, stream>>>(iw + W_OFFS, iw + W_ORD, snd, fw + W_H, fw + W_BES,
                                    fw + W_WGT + OW_R10, fw + W_WGT + OW_R20,
                                    fw + W_WGT + OW_R30, fw + W_A);
    k_node<0><<<NN/4, 256, 0, stream>>>(fw + W_A, fw + W_NF0, fw + W_ATT,
                                        fw + W_WGT + OW_MIX0, fw + W_WGT + OW_SC0,
                                        fw + W_WGT + OW_PR0, fw + W_WGT + OW_RD0, nullptr,
                                        fw + W_NF1, d_out, iw + W_FLAG);
    // interaction 1
    k_h<<<NN/4, 256, 0, stream>>>(fw + W_NF1, fw + W_WGT + OW_UP1, fw + W_H);
    k_msg<<<NN/4, 256, 0, stream>>>(iw + W_OFFS, iw + W_ORD, snd, fw + W_H, fw + W_BES,
                                    fw + W_WGT + OW_R11, fw + W_WGT + OW_R21,
                                    fw + W_WGT + OW_R31, fw + W_A);
    k_node<1><<<NN/4, 256, 0, stream>>>(fw + W_A, fw + W_NF1, fw + W_ATT,
                                        fw + W_WGT + OW_MIX1, fw + W_WGT + OW_SC1,
                                        fw + W_WGT + OW_PR1, fw + W_WGT + OW_ML1,
                                        fw + W_WGT + OW_ML2,
                                        nullptr, d_out, iw + W_FLAG);
}

// Round 5
// 824.790 us; speedup vs baseline: 1.3255x; 1.3255x over previous
//
#include <hip/hip_runtime.h>
#include <hip/hip_bf16.h>
#include <cstdint>
#include <cstddef>

#define NN 10000
#define NE 160000

typedef unsigned short u16;

__device__ __forceinline__ float b2f(u16 u){
    union { uint32_t i; float f; } v; v.i = ((uint32_t)u) << 16; return v.f;
}
__device__ __forceinline__ u16 f2b(float f){
    union { __hip_bfloat16 h; u16 u; } c; c.h = __float2bfloat16(f); return c.u;
}
__device__ __forceinline__ float silu_f(float x){ return x / (1.f + __expf(-x)); }

// ---------------- workspace layout (4-byte word offsets) ----------------
constexpr size_t W_FLAG = 0;                        // 16
constexpr size_t W_CNT  = 16;                       // 10000
constexpr size_t W_OFFS = 10016;                    // 10001
constexpr size_t W_CUR  = 20032;                    // 10000
constexpr size_t W_ORD  = 30032;                    // 160000
constexpr size_t W_SSND = 190032;                   // 160000
constexpr size_t W_ATT  = 350032;                   // 100000
constexpr size_t W_POS  = 450032;                   // 30000
constexpr size_t W_SHF  = 480032;                   // 480000
constexpr size_t W_WGT  = 960032;
constexpr size_t OW_EMB = 0;
constexpr size_t OW_UP0 = 640;
constexpr size_t OW_R10 = 4736;
constexpr size_t OW_R20 = 5248;
constexpr size_t OW_R30 = 9344;
constexpr size_t OW_MIX0= 25728;
constexpr size_t OW_SC0 = 42112;
constexpr size_t OW_PR0 = 83072;
constexpr size_t OW_UP1 = 83264;
constexpr size_t OW_R11 = 87360;
constexpr size_t OW_R21 = 87872;
constexpr size_t OW_R31 = 91968;
constexpr size_t OW_MIX1= 108352;
constexpr size_t OW_SC1 = 124736;
constexpr size_t OW_PR1 = 165696;
constexpr size_t OW_RD0 = 165888;
constexpr size_t OW_ML1 = 165952;
constexpr size_t OW_ML2 = 166976;
// transposed radial weights (for edge-parallel MLP)
constexpr size_t OW_W1T0 = 166992;   // [64][8]
constexpr size_t OW_W2T0 = 167504;   // [64][64]
constexpr size_t OW_W3T0 = 171600;   // [64][64] (l'=0 slice)
constexpr size_t OW_W1T1 = 175696;
constexpr size_t OW_W2T1 = 176208;
constexpr size_t OW_W3T1 = 180304;
constexpr size_t OW_TEND = 184400;
constexpr size_t W_BES  = W_WGT + OW_TEND;          // [E,8] f32 = 1280000
constexpr size_t W_NF0  = W_BES + (size_t)NE*8;     // [N,64]
constexpr size_t W_H    = W_NF0 + (size_t)NN*64;
constexpr size_t W_A    = W_H   + (size_t)NN*64;
constexpr size_t W_NF1  = W_A   + (size_t)NN*64;
constexpr size_t W_R    = W_NF1 + (size_t)NN*64;    // R buffer (tiered)

constexpr size_t NEED_BF16 = (W_R + (size_t)NE*32) * 4;  // ~40.4 MB
constexpr size_t NEED_F32  = (W_R + (size_t)NE*64) * 4;  // ~60.9 MB

// ---------------- dtype detection via exact one-hot structure of attrs ----------------
__global__ void k_detect(const uint32_t* __restrict__ attrs, int* __restrict__ flag){
    __shared__ int cnt_s;
    if (threadIdx.x == 0) cnt_s = 0;
    __syncthreads();
    int c = 0;
    for (int i = threadIdx.x; i < 50000; i += 256){
        uint32_t v = attrs[i];
        if (v != 0u && v != 0x3F800000u) c++;
    }
    atomicAdd(&cnt_s, c);
    __syncthreads();
    if (threadIdx.x == 0) flag[0] = (cnt_s > 100) ? 1 : 0;   // 1 = inputs are bf16
}

// ---------------- convert all float inputs -> fp32 workspace ----------------
struct PrepArgs { const void* s[21]; float* d[21]; int n[21]; };
__global__ void k_prep(PrepArgs a, const int* __restrict__ flag){
    int bf = flag[0];
    int stride = gridDim.x * blockDim.x;
    int t0 = blockIdx.x * blockDim.x + threadIdx.x;
    for (int k = 0; k < 21; k++){
        float* d = a.d[k]; int n = a.n[k];
        if (bf){
            const u16* s = (const u16*)a.s[k];
            for (int i = t0; i < n; i += stride) d[i] = b2f(s[i]);
        } else {
            const float* s = (const float*)a.s[k];
            for (int i = t0; i < n; i += stride) d[i] = s[i];
        }
    }
}

// ---------------- transpose radial weights for the edge-parallel MLP ----------------
__global__ void k_wprep(const float* __restrict__ W1, const float* __restrict__ W2,
                        const float* __restrict__ W3, float* __restrict__ W1T,
                        float* __restrict__ W2T, float* __restrict__ W3T){
    int t = threadIdx.x;
    for (int i = t; i < 512;  i += 256){ int r = i >> 6, f = i & 63; W1T[f*8  + r] = W1[r*64 + f]; }
    for (int i = t; i < 4096; i += 256){ int r = i >> 6, f = i & 63; W2T[f*64 + r] = W2[r*64 + f]; }
    for (int i = t; i < 4096; i += 256){ int r = i >> 6, f = i & 63; W3T[f*64 + r] = W3[r*256 + 4*f]; }
}

// ---------------- edge bessel features ----------------
__global__ void k_geom(const float* __restrict__ pos, const float* __restrict__ shf,
                       const int* __restrict__ snd, const int* __restrict__ rcv,
                       float* __restrict__ bess){
    int e = blockIdx.x * 256 + threadIdx.x;
    if (e >= NE) return;
    int s = snd[e], r = rcv[e];
    float vx = pos[r*3+0] - pos[s*3+0] + shf[e*3+0];
    float vy = pos[r*3+1] - pos[s*3+1] + shf[e*3+1];
    float vz = pos[r*3+2] - pos[s*3+2] + shf[e*3+2];
    float rr = sqrtf(vx*vx + vy*vy + vz*vz);
    float xr = rr * 0.1f;
    float x2 = xr*xr; float x5 = x2*x2*xr;
    float env = 1.f - 21.f*x5 + 35.f*x5*xr - 15.f*x5*x2;
    if (xr >= 1.f) env = 0.f;
    float scl = 0.4472135954999579f * env / (rr + 1e-9f);
    float* be = bess + (size_t)e*8;
    #pragma unroll
    for (int n = 1; n <= 8; n++)
        be[n-1] = scl * sinf((float)n * 3.14159265358979323846f * rr * 0.1f);
}

// ---------------- CSR build ----------------
__global__ void k_hist(const int* __restrict__ rcv, int* __restrict__ cnt){
    int e = blockIdx.x * 256 + threadIdx.x;
    if (e < NE) atomicAdd(&cnt[rcv[e]], 1);
}
__global__ void k_scan(const int* __restrict__ cnt, int* __restrict__ offs, int* __restrict__ cur){
    __shared__ int part[1024];
    int t = threadIdx.x;
    int base = t * 10;
    int s = 0;
    for (int i = 0; i < 10; i++) if (base + i < NN) s += cnt[base + i];
    part[t] = s; __syncthreads();
    for (int d = 1; d < 1024; d <<= 1){
        int v = part[t];
        if (t >= d) v += part[t - d];
        __syncthreads();
        part[t] = v;
        __syncthreads();
    }
    int run = part[t] - s;
    for (int i = 0; i < 10; i++){
        int idx = base + i;
        if (idx < NN){ offs[idx] = run; cur[idx] = run; run += cnt[idx]; }
    }
    if (t == 1023) offs[NN] = part[1023];
}
__global__ void k_scatter(const int* __restrict__ rcv, const int* __restrict__ snd,
                          int* __restrict__ cur, int* __restrict__ order, int* __restrict__ ssnd){
    int e = blockIdx.x * 256 + threadIdx.x;
    if (e < NE){
        int p = atomicAdd(&cur[rcv[e]], 1);
        order[p] = e;
        ssnd[p]  = snd[e];
    }
}

// ---------------- nf0 = attrs @ w_embed ----------------
__global__ void k_embed(const float* __restrict__ attrs, const float* __restrict__ Wemb,
                        float* __restrict__ nf0){
    int t = blockIdx.x * 256 + threadIdx.x;
    int n = t >> 6;
    int l = t & 63;
    float acc = 0.f;
    #pragma unroll
    for (int s = 0; s < 10; s++) acc += attrs[n*10 + s] * Wemb[s*64 + l];
    nf0[n*64 + l] = acc;
}

// ---------------- h = nf(:,:,0) @ W_up ----------------
__global__ void k_h(const float* __restrict__ src, const float* __restrict__ W,
                    float* __restrict__ h){
    int t = blockIdx.x * 256 + threadIdx.x;
    int n = t >> 6;
    int l = t & 63;
    const float* row = src + (size_t)n*64;
    float acc = 0.f;
    #pragma unroll 8
    for (int g = 0; g < 64; g++) acc += row[g] * W[g*64 + l];
    h[n*64 + l] = acc;
}

// ---------------- edge-parallel radial MLP (l'=0 slot): thread = edge ----------------
template<int RF32>
__global__ __launch_bounds__(256) void k_mlp(const float* __restrict__ bess,
        const float* __restrict__ W1T, const float* __restrict__ W2T,
        const float* __restrict__ W3T, void* __restrict__ Rout){
    int e = blockIdx.x * 256 + threadIdx.x;   // NE = 625*256 exact
    float4 q0 = *(const float4*)(bess + (size_t)e*8);
    float4 q1 = *(const float4*)(bess + (size_t)e*8 + 4);
    float h1[64];
    #pragma unroll
    for (int f = 0; f < 64; f++){
        float4 wa = *(const float4*)(W1T + f*8);
        float4 wb = *(const float4*)(W1T + f*8 + 4);
        float a = q0.x*wa.x + q0.y*wa.y + q0.z*wa.z + q0.w*wa.w
                + q1.x*wb.x + q1.y*wb.y + q1.z*wb.z + q1.w*wb.w;
        h1[f] = silu_f(a);
    }
    float h2[64];
    #pragma unroll 8
    for (int f = 0; f < 64; f++){
        float a = 0.f;
        #pragma unroll
        for (int j = 0; j < 64; j += 4){
            float4 w = *(const float4*)(W2T + f*64 + j);
            a += h1[j]*w.x + h1[j+1]*w.y + h1[j+2]*w.z + h1[j+3]*w.w;
        }
        h2[f] = silu_f(a);
    }
    #pragma unroll 1
    for (int f0 = 0; f0 < 64; f0 += 8){
        float r[8];
        #pragma unroll
        for (int k = 0; k < 8; k++){
            int f = f0 + k;
            float a = 0.f;
            #pragma unroll
            for (int j = 0; j < 64; j += 4){
                float4 w = *(const float4*)(W3T + f*64 + j);
                a += h2[j]*w.x + h2[j+1]*w.y + h2[j+2]*w.z + h2[j+3]*w.w;
            }
            r[k] = a;
        }
        if (RF32){
            float* Rf = (float*)Rout + (size_t)e*64 + f0;
            *(float4*)(Rf)     = make_float4(r[0], r[1], r[2], r[3]);
            *(float4*)(Rf + 4) = make_float4(r[4], r[5], r[6], r[7]);
        } else {
            uint32_t p0 = ((uint32_t)f2b(r[1]) << 16) | f2b(r[0]);
            uint32_t p1 = ((uint32_t)f2b(r[3]) << 16) | f2b(r[2]);
            uint32_t p2 = ((uint32_t)f2b(r[5]) << 16) | f2b(r[4]);
            uint32_t p3 = ((uint32_t)f2b(r[7]) << 16) | f2b(r[6]);
            *(uint4*)((u16*)Rout + (size_t)e*64 + f0) = make_uint4(p0, p1, p2, p3);
        }
    }
}

// ---------------- CSR gather-sum: A[n,f] = (1/16) sum_e h[snd,f] * R[e,f] ----------------
template<int RF32>
__global__ __launch_bounds__(256) void k_gather(const int* __restrict__ offs,
        const int* __restrict__ order, const int* __restrict__ ssnd,
        const float* __restrict__ h, const void* __restrict__ R, float* __restrict__ A){
    int wv = threadIdx.x >> 6;
    int n  = blockIdx.x * 4 + wv;
    int l  = threadIdx.x & 63;
    int beg = __builtin_amdgcn_readfirstlane(offs[n]);
    int end = __builtin_amdgcn_readfirstlane(offs[n+1]);
    float acc = 0.f;
    for (int base = beg; base < end; base += 64){
        int cnt = end - base; if (cnt > 64) cnt = 64;
        int idx = base + ((l < cnt) ? l : 0);
        int e_l = order[idx];
        int s_l = ssnd[idx];
        for (int j = 0; j < cnt; j++){
            int e = __shfl(e_l, j);
            int s = __shfl(s_l, j);
            float rv;
            if (RF32) rv = ((const float*)R)[(size_t)e*64 + l];
            else      rv = b2f(((const u16*)R)[(size_t)e*64 + l]);
            acc += h[s*64 + l] * rv;
        }
    }
    A[n*64 + l] = acc * 0.0625f;
}

// ---------------- legacy fused msg (fallback when ws too small for R buffer) ----------------
__global__ __launch_bounds__(256) void k_msg_fused(const int* __restrict__ offs, const int* __restrict__ order,
        const int* __restrict__ snd, const float* __restrict__ h, const float* __restrict__ bess,
        const float* __restrict__ W1, const float* __restrict__ W2, const float* __restrict__ W3,
        float* __restrict__ A){
    int wv = threadIdx.x >> 6;
    int n  = blockIdx.x * 4 + wv;
    int l  = threadIdx.x & 63;
    float w1c[8];
    #pragma unroll
    for (int i = 0; i < 8; i++) w1c[i] = W1[i*64 + l];
    float w2c[64];
    #pragma unroll
    for (int j = 0; j < 64; j++) w2c[j] = W2[j*64 + l];
    float w3c[64];
    #pragma unroll
    for (int j = 0; j < 64; j++) w3c[j] = W3[j*256 + 4*l];
    float acc = 0.f;
    int beg = __builtin_amdgcn_readfirstlane(offs[n]);
    int end = __builtin_amdgcn_readfirstlane(offs[n+1]);
    for (int p = beg; p < end; p++){
        int e = __builtin_amdgcn_readfirstlane(order[p]);
        int s = __builtin_amdgcn_readfirstlane(snd[e]);
        const float* be = bess + (size_t)e*8;
        float h1 = 0.f;
        #pragma unroll
        for (int i = 0; i < 8; i++) h1 += be[i] * w1c[i];
        h1 = silu_f(h1);
        float h2 = 0.f;
        #pragma unroll
        for (int j = 0; j < 64; j++) h2 += __shfl(h1, j) * w2c[j];
        h2 = silu_f(h2);
        float r = 0.f;
        #pragma unroll
        for (int j = 0; j < 64; j++) r += __shfl(h2, j) * w3c[j];
        acc += h[s*64 + l] * r;
    }
    A[n*64 + l] = acc * 0.0625f;
}

// ---------------- node update (mix k=0 + sc + poly) + readout ----------------
template<int LAST>
__global__ __launch_bounds__(256) void k_node(const float* __restrict__ A, const float* __restrict__ nf,
        const float* __restrict__ attrs, const float* __restrict__ Wmix0, const float* __restrict__ Wsc,
        const float* __restrict__ Wprod, const float* __restrict__ Wtail, const float* __restrict__ Wml2,
        float* __restrict__ nf1out, void* __restrict__ out, const int* __restrict__ flag){
    int wv = threadIdx.x >> 6;
    int n  = blockIdx.x * 4 + wv;
    int l  = threadIdx.x & 63;
    float Af  = A[n*64 + l];
    float nff = nf[n*64 + l];
    float am = 0.f;
    #pragma unroll 16
    for (int f = 0; f < 64; f++) am += __shfl(Af, f) * Wmix0[f*64 + l];
    float sc = 0.f;
    for (int s = 0; s < 10; s++){
        float av = attrs[n*10 + s];       // wave-uniform
        if (av != 0.f){
            const float* Ws = Wsc + s*4096;
            float t = 0.f;
            #pragma unroll 16
            for (int f = 0; f < 64; f++) t += __shfl(nff, f) * Ws[f*64 + l];
            sc += av * t;
        }
    }
    float poly = Wprod[l] + Wprod[64 + l]*am + Wprod[128 + l]*am*am;
    float val = am*poly + sc;
    float rv;
    if (LAST == 0){
        nf1out[n*64 + l] = val;
        rv = val * Wtail[l];
    } else {
        // all 64 lanes run the shfl loop (shfl under divergence is UB on CDNA)
        int lj = l & 15;
        float t = 0.f;
        #pragma unroll 16
        for (int g = 0; g < 64; g++){
            float vg = __shfl(val, g);
            t += vg * Wtail[g*16 + lj];
        }
        rv = (l < 16) ? (silu_f(t) * Wml2[lj]) : 0.f;
    }
    #pragma unroll
    for (int o2 = 32; o2; o2 >>= 1) rv += __shfl_down(rv, o2);
    if (l == 0){
        int idx = 2*n + LAST;
        if (flag[0]) ((__hip_bfloat16*)out)[idx] = __float2bfloat16(rv);
        else         ((float*)out)[idx] = rv;
    }
}

// ---------------- launch ----------------
extern "C" void kernel_launch(void* const* d_in, const int* in_sizes, int n_in,
                              void* d_out, int out_size, void* d_ws, size_t ws_size,
                              hipStream_t stream) {
    int*   iw = (int*)d_ws;
    float* fw = (float*)d_ws;
    const int* snd = (const int*)d_in[3];
    const int* rcv = (const int*)d_in[4];

    PrepArgs pa;
    const int    pidx[21] = {0,1,2, 5,6,7,8,9,10,11,12,13,14,15,16,17,18,19,20,21,22};
    const size_t pdst[21] = {W_POS, W_ATT, W_SHF,
        W_WGT+OW_EMB, W_WGT+OW_UP0, W_WGT+OW_R10, W_WGT+OW_R20, W_WGT+OW_R30,
        W_WGT+OW_MIX0, W_WGT+OW_SC0, W_WGT+OW_PR0,
        W_WGT+OW_UP1, W_WGT+OW_R11, W_WGT+OW_R21, W_WGT+OW_R31,
        W_WGT+OW_MIX1, W_WGT+OW_SC1, W_WGT+OW_PR1,
        W_WGT+OW_RD0, W_WGT+OW_ML1, W_WGT+OW_ML2};
    const int    pn[21]   = {30000, 100000, 480000,
        640, 4096, 512, 4096, 16384, 16384, 40960, 192,
        4096, 512, 4096, 16384, 16384, 40960, 192, 64, 1024, 16};
    for (int i = 0; i < 21; i++){
        pa.s[i] = d_in[pidx[i]];
        pa.d[i] = fw + pdst[i];
        pa.n[i] = pn[i];
    }

    const int fastF32  = (ws_size >= NEED_F32);
    const int fastBF16 = (!fastF32 && ws_size >= NEED_BF16);

    hipMemsetAsync(iw + W_CNT, 0, NN * sizeof(int), stream);
    k_detect<<<1, 256, 0, stream>>>((const uint32_t*)d_in[1], iw + W_FLAG);
    k_prep<<<120, 256, 0, stream>>>(pa, iw + W_FLAG);
    if (fastF32 || fastBF16){
        k_wprep<<<1, 256, 0, stream>>>(fw+W_WGT+OW_R10, fw+W_WGT+OW_R20, fw+W_WGT+OW_R30,
                                       fw+W_WGT+OW_W1T0, fw+W_WGT+OW_W2T0, fw+W_WGT+OW_W3T0);
        k_wprep<<<1, 256, 0, stream>>>(fw+W_WGT+OW_R11, fw+W_WGT+OW_R21, fw+W_WGT+OW_R31,
                                       fw+W_WGT+OW_W1T1, fw+W_WGT+OW_W2T1, fw+W_WGT+OW_W3T1);
    }
    k_geom<<<NE/256, 256, 0, stream>>>(fw + W_POS, fw + W_SHF, snd, rcv, fw + W_BES);
    k_hist<<<NE/256, 256, 0, stream>>>(rcv, iw + W_CNT);
    k_scan<<<1, 1024, 0, stream>>>(iw + W_CNT, iw + W_OFFS, iw + W_CUR);
    k_scatter<<<NE/256, 256, 0, stream>>>(rcv, snd, iw + W_CUR, iw + W_ORD, iw + W_SSND);
    k_embed<<<NN/4, 256, 0, stream>>>(fw + W_ATT, fw + W_WGT + OW_EMB, fw + W_NF0);

    // ---- interaction 0 ----
    k_h<<<NN/4, 256, 0, stream>>>(fw + W_NF0, fw + W_WGT + OW_UP0, fw + W_H);
    if (fastF32){
        k_mlp<1><<<NE/256, 256, 0, stream>>>(fw+W_BES, fw+W_WGT+OW_W1T0, fw+W_WGT+OW_W2T0,
                                             fw+W_WGT+OW_W3T0, fw + W_R);
        k_gather<1><<<NN/4, 256, 0, stream>>>(iw+W_OFFS, iw+W_ORD, iw+W_SSND, fw+W_H,
                                              fw + W_R, fw + W_A);
    } else if (fastBF16){
        k_mlp<0><<<NE/256, 256, 0, stream>>>(fw+W_BES, fw+W_WGT+OW_W1T0, fw+W_WGT+OW_W2T0,
                                             fw+W_WGT+OW_W3T0, fw + W_R);
        k_gather<0><<<NN/4, 256, 0, stream>>>(iw+W_OFFS, iw+W_ORD, iw+W_SSND, fw+W_H,
                                              fw + W_R, fw + W_A);
    } else {
        k_msg_fused<<<NN/4, 256, 0, stream>>>(iw+W_OFFS, iw+W_ORD, snd, fw+W_H, fw+W_BES,
                                              fw+W_WGT+OW_R10, fw+W_WGT+OW_R20,
                                              fw+W_WGT+OW_R30, fw + W_A);
    }
    k_node<0><<<NN/4, 256, 0, stream>>>(fw + W_A, fw + W_NF0, fw + W_ATT,
                                        fw + W_WGT + OW_MIX0, fw + W_WGT + OW_SC0,
                                        fw + W_WGT + OW_PR0, fw + W_WGT + OW_RD0, nullptr,
                                        fw + W_NF1, d_out, iw + W_FLAG);

    // ---- interaction 1 ----
    k_h<<<NN/4, 256, 0, stream>>>(fw + W_NF1, fw + W_WGT + OW_UP1, fw + W_H);
    if (fastF32){
        k_mlp<1><<<NE/256, 256, 0, stream>>>(fw+W_BES, fw+W_WGT+OW_W1T1, fw+W_WGT+OW_W2T1,
                                             fw+W_WGT+OW_W3T1, fw + W_R);
        k_gather<1><<<NN/4, 256, 0, stream>>>(iw+W_OFFS, iw+W_ORD, iw+W_SSND, fw+W_H,
                                              fw + W_R, fw + W_A);
    } else if (fastBF16){
        k_mlp<0><<<NE/256, 256, 0, stream>>>(fw+W_BES, fw+W_WGT+OW_W1T1, fw+W_WGT+OW_W2T1,
                                             fw+W_WGT+OW_W3T1, fw + W_R);
        k_gather<0><<<NN/4, 256, 0, stream>>>(iw+W_OFFS, iw+W_ORD, iw+W_SSND, fw+W_H,
                                              fw + W_R, fw + W_A);
    } else {
        k_msg_fused<<<NN/4, 256, 0, stream>>>(iw+W_OFFS, iw+W_ORD, snd, fw+W_H, fw+W_BES,
                                              fw+W_WGT+OW_R11, fw+W_WGT+OW_R21,
                                              fw+W_WGT+OW_R31, fw + W_A);
    }
    k_node<1><<<NN/4, 256, 0, stream>>>(fw + W_A, fw + W_NF1, fw + W_ATT,
                                        fw + W_WGT + OW_MIX1, fw + W_WGT + OW_SC1,
                                        fw + W_WGT + OW_PR1, fw + W_WGT + OW_ML1,
                                        fw + W_WGT + OW_ML2,
                                        nullptr, d_out, iw + W_FLAG);
}